// Round 6
// baseline (66.571 us; speedup 1.0000x reference)
//
#include <hip/hip_runtime.h>
#include <hip/hip_bf16.h>
#include <stdint.h>

#define N_CLOTH     16384
#define N_OBS_VERTS 8192
#define N_OBS_FACES 16384

#define CHUNK 64                         // faces per chunk (LDS tile = 1KB)
#define NC    (N_OBS_FACES / CHUNK)      // 256 chunks
#define VPT   8                          // vertices per thread
#define TB    256                        // threads per block
#define VBLK  (N_CLOTH / (TB * VPT))     // 8 vertex-blocks -> grid 8x256 = 2048 blocks

// ---------------------------------------------------------------------------
// K0: prev-face centers -> faceA[f] = (cx, cy, cz, 0.5*||c||^2)
// Single source of truth for the s-computation inputs; k_nn stages it to LDS
// and k_loss re-reads it (bit-identical values everywhere).
// ---------------------------------------------------------------------------
__global__ __launch_bounds__(256) void k_faces(
    const float* __restrict__ obs_prev, const int* __restrict__ faces,
    float4* __restrict__ faceA)
{
    int f = blockIdx.x * blockDim.x + threadIdx.x;
    if (f >= N_OBS_FACES) return;
    int i0 = faces[3 * f + 0];
    int i1 = faces[3 * f + 1];
    int i2 = faces[3 * f + 2];
    float ax = obs_prev[3 * i0 + 0], ay = obs_prev[3 * i0 + 1], az = obs_prev[3 * i0 + 2];
    float bx = obs_prev[3 * i1 + 0], by = obs_prev[3 * i1 + 1], bz = obs_prev[3 * i1 + 2];
    float cx = obs_prev[3 * i2 + 0], cy = obs_prev[3 * i2 + 1], cz = obs_prev[3 * i2 + 2];
    float pcx = (ax + bx + cx) * (1.0f / 3.0f);
    float pcy = (ay + by + cy) * (1.0f / 3.0f);
    float pcz = (az + bz + cz) * (1.0f / 3.0f);
    float b2h = 0.5f * (pcx * pcx + pcy * pcy + pcz * pcz);
    faceA[f] = make_float4(pcx, pcy, pcz, b2h);
}

// ---------------------------------------------------------------------------
// K1: value-only NN scan. 14 VALU / 4 pairs:
//   12 fma + v_min3(s0,s1,s2) + v_min3(m,s3,best)
// No index tracking -- chunkMin[c][n] = min_{f in chunk c} s(n,f).
// s = 0.5||b||^2 - a.b  (monotone in d2 per vertex; argmin preserved).
// ---------------------------------------------------------------------------
__global__ __launch_bounds__(TB) void k_nn(
    const float* __restrict__ cloth_prev,
    const float4* __restrict__ faceA,
    float* __restrict__ chunkMin)          // [NC][N_CLOTH]
{
    __shared__ float4 tile[CHUNK];
    const int t = threadIdx.x;
    const int bv = blockIdx.x;      // vertex block 0..VBLK-1
    const int c  = blockIdx.y;      // face chunk   0..NC-1
    const int fbase = c * CHUNK;

    if (t < CHUNK) tile[t] = faceA[fbase + t];

    float vx[VPT], vy[VPT], vz[VPT], best[VPT];
#pragma unroll
    for (int j = 0; j < VPT; ++j) {
        int n = bv * (TB * VPT) + j * TB + t;
        vx[j] = cloth_prev[3 * n + 0];
        vy[j] = cloth_prev[3 * n + 1];
        vz[j] = cloth_prev[3 * n + 2];
        best[j] = 3.4e38f;
    }
    __syncthreads();

#pragma unroll 2
    for (int gi = 0; gi < CHUNK / 4; ++gi) {
        float4 b0 = tile[4 * gi + 0];
        float4 b1 = tile[4 * gi + 1];
        float4 b2 = tile[4 * gi + 2];
        float4 b3 = tile[4 * gi + 3];
#pragma unroll
        for (int j = 0; j < VPT; ++j) {
            float s0 = fmaf(-vx[j], b0.x, b0.w);
            s0 = fmaf(-vy[j], b0.y, s0);
            s0 = fmaf(-vz[j], b0.z, s0);
            float s1 = fmaf(-vx[j], b1.x, b1.w);
            s1 = fmaf(-vy[j], b1.y, s1);
            s1 = fmaf(-vz[j], b1.z, s1);
            float s2 = fmaf(-vx[j], b2.x, b2.w);
            s2 = fmaf(-vy[j], b2.y, s2);
            s2 = fmaf(-vz[j], b2.z, s2);
            float s3 = fmaf(-vx[j], b3.x, b3.w);
            s3 = fmaf(-vy[j], b3.y, s3);
            s3 = fmaf(-vz[j], b3.z, s3);
            float m = fminf(fminf(s0, s1), s2);       // v_min3_f32
            best[j] = fminf(fminf(m, s3), best[j]);   // v_min3_f32
        }
    }

#pragma unroll
    for (int j = 0; j < VPT; ++j) {
        int n = bv * (TB * VPT) + j * TB + t;
        chunkMin[(size_t)c * N_CLOTH + n] = best[j];
    }
}

// ---------------------------------------------------------------------------
// K2: per vertex -- scan 256 chunk minima (strict <, earliest chunk wins
// ties; chunk order == face order so this preserves jnp.argmin tie-break),
// re-scan winning chunk with bit-identical fmaf chain, take lowest q with
// s == m* (descending select). Then cubic penalty + block sum.
// ---------------------------------------------------------------------------
__global__ __launch_bounds__(256) void k_loss(
    const float* __restrict__ cloth_prev,
    const float* __restrict__ cloth_pred,
    const float4* __restrict__ faceA,
    const float* __restrict__ chunkMin,
    const float* __restrict__ obs_pos,
    const int* __restrict__ faces,
    float* __restrict__ lossPartial)
{
    const int t = threadIdx.x;
    const int n = blockIdx.x * blockDim.x + t;

    float vx = cloth_prev[3 * n + 0];
    float vy = cloth_prev[3 * n + 1];
    float vz = cloth_prev[3 * n + 2];

    // phase 1: winning chunk (earliest on ties)
    float m = chunkMin[n];
    int cb = 0;
#pragma unroll 8
    for (int c = 1; c < NC; ++c) {
        float v = chunkMin[(size_t)c * N_CLOTH + n];
        cb = (v < m) ? c : cb;
        m = fminf(v, m);
    }

    // phase 2: lowest face in winning chunk with s == m (bit-exact recompute)
    const int fbase = cb * CHUNK;
    int idx = fbase + CHUNK - 1;
#pragma unroll 4
    for (int q = CHUNK - 1; q >= 0; --q) {
        float4 b = faceA[fbase + q];
        float s = fmaf(-vx, b.x, b.w);
        s = fmaf(-vy, b.y, s);
        s = fmaf(-vz, b.z, s);
        idx = (s == m) ? fbase + q : idx;
    }

    // loss math on chosen face
    int i0 = faces[3 * idx + 0];
    int i1 = faces[3 * idx + 1];
    int i2 = faces[3 * idx + 2];
    float ux = obs_pos[3 * i0 + 0], uy = obs_pos[3 * i0 + 1], uz = obs_pos[3 * i0 + 2];
    float wx1 = obs_pos[3 * i1 + 0], wy1 = obs_pos[3 * i1 + 1], wz1 = obs_pos[3 * i1 + 2];
    float wx2 = obs_pos[3 * i2 + 0], wy2 = obs_pos[3 * i2 + 1], wz2 = obs_pos[3 * i2 + 2];

    float fpx = (ux + wx1 + wx2) * (1.0f / 3.0f);
    float fpy = (uy + wy1 + wy2) * (1.0f / 3.0f);
    float fpz = (uz + wz1 + wz2) * (1.0f / 3.0f);

    float e1x = wx1 - ux, e1y = wy1 - uy, e1z = wz1 - uz;
    float e2x = wx2 - ux, e2y = wy2 - uy, e2z = wz2 - uz;
    float nx = e1y * e2z - e1z * e2y;
    float ny = e1z * e2x - e1x * e2z;
    float nz = e1x * e2y - e1y * e2x;
    float nrm = sqrtf(nx * nx + ny * ny + nz * nz);
    float inv = 1.0f / fmaxf(nrm, 1e-12f);

    float px = cloth_pred[3 * n + 0];
    float py = cloth_pred[3 * n + 1];
    float pz = cloth_pred[3 * n + 2];
    float d = (px - fpx) * nx * inv + (py - fpy) * ny * inv + (pz - fpz) * nz * inv;
    float tt = fmaxf(1e-3f - d, 0.0f);
    float val = tt * tt * tt;

    __shared__ float red[256];
    red[t] = val;
    __syncthreads();
    for (int s = 128; s > 0; s >>= 1) {
        if (t < s) red[t] += red[t + s];
        __syncthreads();
    }
    if (t == 0) lossPartial[blockIdx.x] = red[0];
}

// ---------------------------------------------------------------------------
// K3: final 64-partial sum * weight(iteration) -> d_out[0] (pure overwrite,
// no memset node needed)
// ---------------------------------------------------------------------------
__global__ __launch_bounds__(64) void k_final(
    const float* __restrict__ lossPartial,
    const int* __restrict__ iteration,
    float* __restrict__ out)
{
    int t = threadIdx.x;
    float v = lossPartial[t];
#pragma unroll
    for (int o = 32; o > 0; o >>= 1) v += __shfl_down(v, o);
    if (t == 0) {
        int it = iteration[0];
        float itf = fmaxf((float)(it - 50000), 0.0f);
        float prog = fminf(itf * (1.0f / 100000.0f), 1.0f);
        float w = 1.0f + (5000.0f - 1.0f) * prog;
        out[0] = v * w;
    }
}

extern "C" void kernel_launch(void* const* d_in, const int* in_sizes, int n_in,
                              void* d_out, int out_size, void* d_ws, size_t ws_size,
                              hipStream_t stream) {
    const float* obs_pos    = (const float*)d_in[0];
    const float* obs_prev   = (const float*)d_in[1];
    const int*   faces      = (const int*)d_in[2];
    const float* cloth_prev = (const float*)d_in[3];
    const float* cloth_pred = (const float*)d_in[4];
    const int*   iteration  = (const int*)d_in[5];
    float* out = (float*)d_out;

    char* ws = (char*)d_ws;
    float4* faceA      = (float4*)(ws);                       // 256 KB
    float*  chunkMin   = (float*)(ws + 262144);               // 16.8 MB [NC][N]
    float*  lossPartial = (float*)(ws + 262144 + 16777216);   // 256 B (64 used)

    k_faces<<<N_OBS_FACES / 256, 256, 0, stream>>>(obs_prev, faces, faceA);
    k_nn<<<dim3(VBLK, NC), TB, 0, stream>>>(cloth_prev, faceA, chunkMin);
    k_loss<<<N_CLOTH / 256, 256, 0, stream>>>(cloth_prev, cloth_pred, faceA,
                                              chunkMin, obs_pos, faces, lossPartial);
    k_final<<<1, 64, 0, stream>>>(lossPartial, iteration, out);
}

// Round 7
// 43.612 us; speedup vs baseline: 1.5264x; 1.5264x over previous
//
#include <hip/hip_runtime.h>
#include <hip/hip_bf16.h>
#include <stdint.h>

#define N_CLOTH     16384
#define N_OBS_VERTS 8192
#define N_OBS_FACES 16384

#define CHUNK 128                        // faces per chunk (LDS tile = 2KB)
#define NC    (N_OBS_FACES / CHUNK)      // 128 chunks
#define VPT   8                          // vertices per thread
#define TB    256                        // threads per block
#define VBLK  (N_CLOTH / (TB * VPT))     // 8 vertex-blocks -> grid 8x128 = 1024 blocks

// ---------------------------------------------------------------------------
// K0: prev-face centers -> faceA[f] = (cx, cy, cz, 0.5*||c||^2)
// Single source of truth: k_nn stages it; k_reduce re-reads it bit-identically.
// ---------------------------------------------------------------------------
__global__ __launch_bounds__(256) void k_faces(
    const float* __restrict__ obs_prev, const int* __restrict__ faces,
    float4* __restrict__ faceA)
{
    int f = blockIdx.x * blockDim.x + threadIdx.x;
    if (f >= N_OBS_FACES) return;
    int i0 = faces[3 * f + 0];
    int i1 = faces[3 * f + 1];
    int i2 = faces[3 * f + 2];
    float ax = obs_prev[3 * i0 + 0], ay = obs_prev[3 * i0 + 1], az = obs_prev[3 * i0 + 2];
    float bx = obs_prev[3 * i1 + 0], by = obs_prev[3 * i1 + 1], bz = obs_prev[3 * i1 + 2];
    float cx = obs_prev[3 * i2 + 0], cy = obs_prev[3 * i2 + 1], cz = obs_prev[3 * i2 + 2];
    float pcx = (ax + bx + cx) * (1.0f / 3.0f);
    float pcy = (ay + by + cy) * (1.0f / 3.0f);
    float pcz = (az + bz + cz) * (1.0f / 3.0f);
    float b2h = 0.5f * (pcx * pcx + pcy * pcy + pcz * pcz);
    faceA[f] = make_float4(pcx, pcy, pcz, b2h);
}

// ---------------------------------------------------------------------------
// K1: value-only NN scan. 14 VALU / 4 pairs:
//   12 fma + v_min3(s0,s1,s2) + v_min3(m,s3,best)
// chunkMin[c][n] = min_{f in chunk c} s(n,f),  s = 0.5||b||^2 - a.b
// (monotone in d2 per vertex; min3/fminf return one of their inputs, so the
//  min is bit-equal to some s -- k_reduce relies on that for index recovery)
// ---------------------------------------------------------------------------
__global__ __launch_bounds__(TB) void k_nn(
    const float* __restrict__ cloth_prev,
    const float4* __restrict__ faceA,
    float* __restrict__ chunkMin)          // [NC][N_CLOTH]
{
    __shared__ float4 tile[CHUNK];
    const int t = threadIdx.x;
    const int bv = blockIdx.x;      // vertex block 0..VBLK-1
    const int c  = blockIdx.y;      // face chunk   0..NC-1
    const int fbase = c * CHUNK;

    if (t < CHUNK) tile[t] = faceA[fbase + t];

    float vx[VPT], vy[VPT], vz[VPT], best[VPT];
#pragma unroll
    for (int j = 0; j < VPT; ++j) {
        int n = bv * (TB * VPT) + j * TB + t;
        vx[j] = cloth_prev[3 * n + 0];
        vy[j] = cloth_prev[3 * n + 1];
        vz[j] = cloth_prev[3 * n + 2];
        best[j] = 3.4e38f;
    }
    __syncthreads();

#pragma unroll 2
    for (int gi = 0; gi < CHUNK / 4; ++gi) {
        float4 b0 = tile[4 * gi + 0];
        float4 b1 = tile[4 * gi + 1];
        float4 b2 = tile[4 * gi + 2];
        float4 b3 = tile[4 * gi + 3];
#pragma unroll
        for (int j = 0; j < VPT; ++j) {
            float s0 = fmaf(-vx[j], b0.x, b0.w);
            s0 = fmaf(-vy[j], b0.y, s0);
            s0 = fmaf(-vz[j], b0.z, s0);
            float s1 = fmaf(-vx[j], b1.x, b1.w);
            s1 = fmaf(-vy[j], b1.y, s1);
            s1 = fmaf(-vz[j], b1.z, s1);
            float s2 = fmaf(-vx[j], b2.x, b2.w);
            s2 = fmaf(-vy[j], b2.y, s2);
            s2 = fmaf(-vz[j], b2.z, s2);
            float s3 = fmaf(-vx[j], b3.x, b3.w);
            s3 = fmaf(-vy[j], b3.y, s3);
            s3 = fmaf(-vz[j], b3.z, s3);
            float m = fminf(fminf(s0, s1), s2);       // v_min3_f32
            best[j] = fminf(fminf(m, s3), best[j]);   // v_min3_f32
        }
    }

#pragma unroll
    for (int j = 0; j < VPT; ++j) {
        int n = bv * (TB * VPT) + j * TB + t;
        chunkMin[(size_t)c * N_CLOTH + n] = best[j];
    }
}

// ---------------------------------------------------------------------------
// K2: 4 threads per vertex (grid 256 blocks x 256 thr = 4 waves/CU).
// phase 1: each thread key-min's 32 chunks; key = (mono(v)<<32)|c -> global
//          min == smallest value, earliest chunk on ties (jnp.argmin order).
// phase 2: each thread rescans 32 faces of the winning chunk with the
//          bit-identical fmaf chain; descending select -> lowest matching q.
// leader thread does the loss math; block-sum -> lossPartial[block].
// ---------------------------------------------------------------------------
__global__ __launch_bounds__(256) void k_reduce(
    const float* __restrict__ cloth_prev,
    const float* __restrict__ cloth_pred,
    const float4* __restrict__ faceA,
    const float* __restrict__ chunkMin,
    const float* __restrict__ obs_pos,
    const int* __restrict__ faces,
    float* __restrict__ lossPartial)
{
    const int t = threadIdx.x;
    const int r = t & 3;                       // role within vertex
    const int n = blockIdx.x * 64 + (t >> 2);  // vertex id

    // ---- phase 1: min over this thread's 32 chunks (as u64 keys) ----
    unsigned long long key = 0xFFFFFFFFFFFFFFFFull;
#pragma unroll 8
    for (int i = 0; i < NC / 4; ++i) {
        int c = r * (NC / 4) + i;
        float v = chunkMin[(size_t)c * N_CLOTH + n];
        unsigned int ub = __float_as_uint(v);
        ub = (ub & 0x80000000u) ? ~ub : (ub | 0x80000000u);   // monotone map
        unsigned long long k = ((unsigned long long)ub << 32) | (unsigned int)c;
        key = (k < key) ? k : key;
    }
    {
        unsigned long long o = __shfl_xor(key, 1);
        key = (o < key) ? o : key;
        o = __shfl_xor(key, 2);
        key = (o < key) ? o : key;
    }
    const int cb = (int)(unsigned int)(key & 0xFFFFFFFFull);
    unsigned int ubm = (unsigned int)(key >> 32);
    ubm = (ubm & 0x80000000u) ? (ubm & 0x7FFFFFFFu) : ~ubm;   // inverse map
    const float m = __uint_as_float(ubm);

    // ---- phase 2: lowest face in chunk cb with s == m (bit-exact) ----
    const float vx = cloth_prev[3 * n + 0];
    const float vy = cloth_prev[3 * n + 1];
    const float vz = cloth_prev[3 * n + 2];
    const int fbase = cb * CHUNK;
    int match = 0x7FFFFFFF;
#pragma unroll 8
    for (int qq = CHUNK / 4 - 1; qq >= 0; --qq) {
        int q = r * (CHUNK / 4) + qq;
        float4 b = faceA[fbase + q];
        float s = fmaf(-vx, b.x, b.w);
        s = fmaf(-vy, b.y, s);
        s = fmaf(-vz, b.z, s);
        match = (s == m) ? q : match;          // descending -> lowest q wins
    }
    {
        int o = __shfl_xor(match, 1);
        match = (o < match) ? o : match;
        o = __shfl_xor(match, 2);
        match = (o < match) ? o : match;
    }
    const int idx = fbase + match;

    // ---- leader computes the loss term ----
    float val = 0.0f;
    if (r == 0) {
        int i0 = faces[3 * idx + 0];
        int i1 = faces[3 * idx + 1];
        int i2 = faces[3 * idx + 2];
        float ux = obs_pos[3 * i0 + 0], uy = obs_pos[3 * i0 + 1], uz = obs_pos[3 * i0 + 2];
        float wx1 = obs_pos[3 * i1 + 0], wy1 = obs_pos[3 * i1 + 1], wz1 = obs_pos[3 * i1 + 2];
        float wx2 = obs_pos[3 * i2 + 0], wy2 = obs_pos[3 * i2 + 1], wz2 = obs_pos[3 * i2 + 2];

        float fpx = (ux + wx1 + wx2) * (1.0f / 3.0f);
        float fpy = (uy + wy1 + wy2) * (1.0f / 3.0f);
        float fpz = (uz + wz1 + wz2) * (1.0f / 3.0f);

        float e1x = wx1 - ux, e1y = wy1 - uy, e1z = wz1 - uz;
        float e2x = wx2 - ux, e2y = wy2 - uy, e2z = wz2 - uz;
        float nx = e1y * e2z - e1z * e2y;
        float ny = e1z * e2x - e1x * e2z;
        float nz = e1x * e2y - e1y * e2x;
        float nrm = sqrtf(nx * nx + ny * ny + nz * nz);
        float inv = 1.0f / fmaxf(nrm, 1e-12f);

        float px = cloth_pred[3 * n + 0];
        float py = cloth_pred[3 * n + 1];
        float pz = cloth_pred[3 * n + 2];
        float d = (px - fpx) * nx * inv + (py - fpy) * ny * inv + (pz - fpz) * nz * inv;
        float tt = fmaxf(1e-3f - d, 0.0f);
        val = tt * tt * tt;
    }

    __shared__ float red[256];
    red[t] = val;
    __syncthreads();
    for (int s = 128; s > 0; s >>= 1) {
        if (t < s) red[t] += red[t + s];
        __syncthreads();
    }
    if (t == 0) lossPartial[blockIdx.x] = red[0];
}

// ---------------------------------------------------------------------------
// K3: final 256-partial sum * weight(iteration) -> d_out[0] (pure overwrite)
// ---------------------------------------------------------------------------
__global__ __launch_bounds__(64) void k_final(
    const float* __restrict__ lossPartial,
    const int* __restrict__ iteration,
    float* __restrict__ out)
{
    int t = threadIdx.x;
    float v = lossPartial[t] + lossPartial[t + 64] +
              lossPartial[t + 128] + lossPartial[t + 192];
#pragma unroll
    for (int o = 32; o > 0; o >>= 1) v += __shfl_down(v, o);
    if (t == 0) {
        int it = iteration[0];
        float itf = fmaxf((float)(it - 50000), 0.0f);
        float prog = fminf(itf * (1.0f / 100000.0f), 1.0f);
        float w = 1.0f + (5000.0f - 1.0f) * prog;
        out[0] = v * w;
    }
}

extern "C" void kernel_launch(void* const* d_in, const int* in_sizes, int n_in,
                              void* d_out, int out_size, void* d_ws, size_t ws_size,
                              hipStream_t stream) {
    const float* obs_pos    = (const float*)d_in[0];
    const float* obs_prev   = (const float*)d_in[1];
    const int*   faces      = (const int*)d_in[2];
    const float* cloth_prev = (const float*)d_in[3];
    const float* cloth_pred = (const float*)d_in[4];
    const int*   iteration  = (const int*)d_in[5];
    float* out = (float*)d_out;

    char* ws = (char*)d_ws;
    float4* faceA       = (float4*)(ws);                              // 256 KB
    float*  chunkMin    = (float*)(ws + 262144);                      // 8.4 MB [NC][N]
    float*  lossPartial = (float*)(ws + 262144 + 8388608);            // 1 KB (256 used)

    k_faces<<<N_OBS_FACES / 256, 256, 0, stream>>>(obs_prev, faces, faceA);
    k_nn<<<dim3(VBLK, NC), TB, 0, stream>>>(cloth_prev, faceA, chunkMin);
    k_reduce<<<N_CLOTH * 4 / 256, 256, 0, stream>>>(cloth_prev, cloth_pred, faceA,
                                                    chunkMin, obs_pos, faces, lossPartial);
    k_final<<<1, 64, 0, stream>>>(lossPartial, iteration, out);
}